// Round 14
// baseline (577.925 us; speedup 1.0000x reference)
//
#include <hip/hip_runtime.h>
#include <hip/hip_cooperative_groups.h>
#include <math.h>

namespace cg = cooperative_groups;

#define N_SPK 32
#define D_CH 1128
#define V_FR 100
#define NFEAT 13
#define CHUNK (V_FR * NFEAT)   // 1300 floats per (b,d) slab
#define CHUNK4 (CHUNK / 4)     // 325 float4s
#define BN_EPS 1e-5f
#define A_GROUPS 8             // stats kernel: 8 groups of 4 speakers
#define A_SPK 4
// uA layout: [0..12] u, [13] sA, [14..104] Btri (upper-tri of A+A^T, diag=A_ii)
#define UOFF_SA 13
#define UOFF_B  14
#define TRI(i, j) ((i) * NFEAT - (i) * ((i) - 1) / 2 + ((j) - (i)))   // j >= i

__device__ __forceinline__ float wave_sum(float v) {
    #pragma unroll
    for (int off = 1; off < 64; off <<= 1) v += __shfl_xor(v, off, 64);
    return v;
}
__device__ __forceinline__ float tanh_fast(float x) {
    // 1 - 2/(e^{2x}+1); v_exp + v_rcp. Saturates to +/-1 correctly.
    float e = __expf(2.f * x);
    return fmaf(-2.f, __builtin_amdgcn_rcpf(e + 1.f), 1.f);
}

// ---------- A: bn2d partial stats. grid = A_GROUPS x D, block 256 ----------
__global__ __launch_bounds__(256)
void stats_kernel(const float* __restrict__ X1, const float* __restrict__ X2,
                  float4* __restrict__ partial)   // [D][A_GROUPS] = {s1,q1,s2,q2}
{
    const int tid  = threadIdx.x;
    const int wave = tid >> 6, lane = tid & 63;
    const int d  = blockIdx.x % D_CH;
    const int g  = blockIdx.x / D_CH;    // 0..7
    const int b0 = g * A_SPK;
    __shared__ float red[4][4];

    float s1 = 0.f, q1 = 0.f, s2 = 0.f, q2 = 0.f;
    #pragma unroll
    for (int c = 0; c < A_SPK; ++c) {
        const float4* p1 = (const float4*)(X1 + ((size_t)(b0 + c) * D_CH + d) * CHUNK);
        const float4* p2 = (const float4*)(X2 + ((size_t)(b0 + c) * D_CH + d) * CHUNK);
        for (int pos = tid; pos < CHUNK4; pos += 256) {
            float4 v = p1[pos];
            s1 += v.x + v.y + v.z + v.w;
            q1 += fmaf(v.x, v.x, fmaf(v.y, v.y, fmaf(v.z, v.z, v.w * v.w)));
            float4 w = p2[pos];
            s2 += w.x + w.y + w.z + w.w;
            q2 += fmaf(w.x, w.x, fmaf(w.y, w.y, fmaf(w.z, w.z, w.w * w.w)));
        }
    }
    s1 = wave_sum(s1); q1 = wave_sum(q1); s2 = wave_sum(s2); q2 = wave_sum(q2);
    if (lane == 0) { red[wave][0] = s1; red[wave][1] = q1; red[wave][2] = s2; red[wave][3] = q2; }
    __syncthreads();
    if (tid == 0) {
        float S1 = 0.f, Q1 = 0.f, S2 = 0.f, Q2 = 0.f;
        for (int w = 0; w < 4; ++w) { S1 += red[w][0]; Q1 += red[w][1]; S2 += red[w][2]; Q2 += red[w][3]; }
        partial[d * A_GROUPS + g] = make_float4(S1, Q1, S2, Q2);
    }
}

// ---------- B: finalize coefs per d; block 0 also precomputes u, sA, Btri ----------
__global__ __launch_bounds__(256)
void coef_kernel(const float4* __restrict__ partial, const float* __restrict__ attn_w,
                 const float* __restrict__ g2d, const float* __restrict__ b2d,
                 float4* __restrict__ coefs, float* __restrict__ uA)
{
    const int d = blockIdx.x * 256 + threadIdx.x;
    if (blockIdx.x == 0 && threadIdx.x < NFEAT) {
        int i = threadIdx.x;
        float s = 0.f;
        for (int j = 0; j < NFEAT; ++j) s += attn_w[i * NFEAT + j] + attn_w[j * NFEAT + i];
        uA[i] = s;                       // u = A*1 + A^T*1 (same for A=W^T as for W)
    }
    if (blockIdx.x == 0 && threadIdx.x == NFEAT) {
        float s = 0.f;
        for (int k = 0; k < NFEAT * NFEAT; ++k) s += attn_w[k];
        uA[UOFF_SA] = s;                 // sA = 1^T A 1
    }
    if (blockIdx.x == 0 && threadIdx.x < NFEAT * NFEAT) {
        int i = threadIdx.x / NFEAT, j = threadIdx.x % NFEAT;
        if (j >= i) {
            float v = (j == i) ? attn_w[i * NFEAT + i]
                               : attn_w[i * NFEAT + j] + attn_w[j * NFEAT + i];
            uA[UOFF_B + TRI(i, j)] = v;  // x^T A x = sum_i x_i * (sum_{j>=i} B_ij x_j)
        }
    }
    if (d >= D_CH) return;
    float S1 = 0.f, Q1 = 0.f, S2 = 0.f, Q2 = 0.f;
    for (int g = 0; g < A_GROUPS; ++g) {
        float4 p = partial[d * A_GROUPS + g];
        S1 += p.x; Q1 += p.y; S2 += p.z; Q2 += p.w;
    }
    const float inv = 1.0f / (float)(N_SPK * V_FR * NFEAT);
    float m1 = S1 * inv, v1 = Q1 * inv - m1 * m1;
    float m2 = S2 * inv, v2 = Q2 * inv - m2 * m2;
    float gd = g2d[d], bd = b2d[d];
    float a1 = gd * rsqrtf(v1 + BN_EPS);
    float a2 = gd * rsqrtf(v2 + BN_EPS);
    coefs[d] = make_float4(a1, bd - m1 * a1, a2, bd - m2 * a2);
}

// quadform + softmax weights on already-loaded registers (round-8/10/12 verified).
__device__ __forceinline__ void quad_pass(const float x0[NFEAT], const float x1[NFEAT],
                                          float m0, float m1v, bool has1,
                                          const float* __restrict__ uA,
                                          float aa, float cc, float sA,
                                          float part[NFEAT], float* den)
{
    float q0 = 0.f, r0 = 0.f, q1f = 0.f, r1f = 0.f;
    #pragma unroll
    for (int i = 0; i < NFEAT; ++i) {
        float bii = uA[UOFF_B + TRI(i, i)];      // uniform -> s_load (scalar pipe)
        float y0 = bii * x0[i];
        float y1 = bii * x1[i];
        #pragma unroll
        for (int j = i + 1; j < NFEAT; ++j) {
            float bij = uA[UOFF_B + TRI(i, j)];  // uniform -> s_load
            y0 = fmaf(bij, x0[j], y0);
            y1 = fmaf(bij, x1[j], y1);
        }
        float ui = uA[i];                        // uniform -> s_load
        q0  = fmaf(x0[i], y0, q0);
        q1f = fmaf(x1[i], y1, q1f);
        r0  = fmaf(ui, x0[i], r0);
        r1f = fmaf(ui, x1[i], r1f);
    }
    float S0 = fmaf(aa * aa, q0,  fmaf(aa * cc, r0,  cc * cc * sA));
    float S1 = fmaf(aa * aa, q1f, fmaf(aa * cc, r1f, cc * cc * sA));
    // no max-subtraction (logits tanh-bounded); mask as multiplier
    float e0 = m0 * __expf(tanh_fast(S0));
    float e1 = has1 ? m1v * __expf(tanh_fast(S1)) : 0.f;
    *den = e0 + e1;
    #pragma unroll
    for (int i = 0; i < NFEAT; ++i) part[i] = fmaf(e0, x0[i], e1 * x1[i]);
}

__device__ __forceinline__ void load_frames(const float* __restrict__ xw, int lane, bool has1,
                                            float x0[NFEAT], float x1[NFEAT]) {
    const float* p = xw + lane * NFEAT;
    #pragma unroll
    for (int i = 0; i < NFEAT; ++i) x0[i] = p[i];
    if (has1) {
        const float* p2 = xw + (lane + 64) * NFEAT;
        #pragma unroll
        for (int i = 0; i < NFEAT; ++i) x1[i] = p2[i];
    } else {
        #pragma unroll
        for (int i = 0; i < NFEAT; ++i) x1[i] = 0.f;
    }
}

// ---------- C: attention. One wave = one (b,d) pair. Early-issued X2 ----------
// R12 + early X2: ALL global loads (X1, X2, masks) issue up front, so no HBM/L3
// latency is exposed between pass 1 and pass 2. R11's version of this spilled
// because the unconstrained allocator chose VGPR=44; __launch_bounds__(128,5)
// caps at ~102 (need ~85 peak) at the occupancy R12 actually achieved (~4.9/SIMD).
__global__ __launch_bounds__(128, 5)
void attend_kernel(const float* __restrict__ X1, const float* __restrict__ X2,
                   const float* __restrict__ M1, const float* __restrict__ M2,
                   const float4* __restrict__ coefs, const float* __restrict__ uA,
                   float* __restrict__ feats)
{
    const int tid  = threadIdx.x;
    const int wave = tid >> 6, lane = tid & 63;
    __shared__ float xs[2][CHUNK];   // one slab per wave, reused X1 then X2 = 10.4 KB
    float* xw = xs[wave];

    const int u = blockIdx.x * 2 + wave;      // 0..36095
    const int d = u % D_CH;
    const int b = N_SPK - 1 - (u / D_CH);     // reversed for L3 reuse after stats

    const float4 cf = coefs[d];
    const float a1 = cf.x, c1 = cf.y, a2 = cf.z, c2 = cf.w;
    const float sA = uA[UOFF_SA];

    const size_t base = ((size_t)b * D_CH + d) * CHUNK;
    const bool  has1 = lane < (V_FR - 64);

    // masks: strided (4 instrs/wave), issued first, consumed late
    float m0a = M1[base + (size_t)lane * NFEAT];
    float m1a = has1 ? M1[base + (size_t)(lane + 64) * NFEAT] : 0.f;
    float m0b = M2[base + (size_t)lane * NFEAT];
    float m1b = has1 ? M2[base + (size_t)(lane + 64) * NFEAT] : 0.f;

    // X2 issued EARLY into registers (held across pass 1; capped regalloc, no spill)
    float4 r2[6];
    {
        const float4* s2 = (const float4*)(X2 + base);
        #pragma unroll
        for (int k = 0; k < 5; ++k) r2[k] = s2[lane + 64 * k];
        r2[5] = (lane < 5) ? s2[320 + lane] : make_float4(0.f, 0.f, 0.f, 0.f);
    }
    // X1 staged directly (transient regs)
    {
        const float4* s1 = (const float4*)(X1 + base);
        float4* w1 = (float4*)xw;
        #pragma unroll
        for (int k = 0; k < 5; ++k) w1[lane + 64 * k] = s1[lane + 64 * k];
        if (lane < 5) w1[320 + lane] = s1[320 + lane];
    }
    __syncthreads();   // X1 staged

    float x0[NFEAT], x1v[NFEAT];
    float part1[NFEAT], part2[NFEAT], den1, den2;

    // pass 1: X1
    load_frames(xw, lane, has1, x0, x1v);
    quad_pass(x0, x1v, m0a, m1a, has1, uA, a1, c1, sA, part1, &den1);
    __syncthreads();   // all pass-1 LDS reads retired before overwrite (WAR)

    // stage X2 from registers (no global latency here)
    {
        float4* w2 = (float4*)xw;
        #pragma unroll
        for (int k = 0; k < 5; ++k) w2[lane + 64 * k] = r2[k];
        if (lane < 5) w2[320 + lane] = r2[5];
    }
    __syncthreads();   // X2 staged

    // pass 2: X2
    load_frames(xw, lane, has1, x0, x1v);
    quad_pass(x0, x1v, m0b, m1b, has1, uA, a2, c2, sA, part2, &den2);

    den1 = wave_sum(den1);
    den2 = wave_sum(den2);
    const float wt1 = a1 / den1;
    const float wt2 = a2 / den2;

    // pair-combined per-lane value; one 13-reg butterfly (verified)
    float q[NFEAT];
    #pragma unroll
    for (int i = 0; i < NFEAT; ++i) q[i] = fmaf(wt1, part1[i], -wt2 * part2[i]);
    #pragma unroll
    for (int off = 1; off < 64; off <<= 1) {
        #pragma unroll
        for (int i = 0; i < NFEAT; ++i) q[i] += __shfl_xor(q[i], off, 64);
    }

    if (lane == 0) {   // lane 0's m0a/m0b are M[b,d,0,0]
        const float dc = c1 - c2;
        float ss = 0.f;
        #pragma unroll
        for (int i = 0; i < NFEAT; ++i) {
            float diff = q[i] + dc;
            ss = fmaf(diff, diff, ss);
        }
        float f  = logf(ss + 1e-5f);
        float pm = (m0a + m0b == 2.0f) ? 1.0f : 0.0f;
        feats[(size_t)b * D_CH + d] = (f + 1.0f) * pm - 1.0f;
    }
}

// ---------- D: BatchNorm1d over speakers. grid = 141, block 256 (8 d's) ----------
__global__ __launch_bounds__(256)
void bn1_kernel(const float* __restrict__ feats, const float* __restrict__ g1,
                const float* __restrict__ b1, float* __restrict__ xout)
{
    const int tid = threadIdx.x;
    const int n = tid & 31, dl = tid >> 5;
    const int d = blockIdx.x * 8 + dl;
    float f = feats[(size_t)n * D_CH + d];
    float s = f, sq = f * f;
    #pragma unroll
    for (int off = 1; off < 32; off <<= 1) { s += __shfl_xor(s, off, 64); sq += __shfl_xor(sq, off, 64); }
    float mean = s * (1.0f / 32.0f);
    float var  = sq * (1.0f / 32.0f) - mean * mean;
    xout[(size_t)n * D_CH + d] = (f - mean) * rsqrtf(var + BN_EPS) * g1[d] + b1[d];
}

// ---------- MLP: one cooperative kernel, 7 layers with grid.sync ----------
// 250 blocks x 256 thr (co-resident: 250 <= 256 CUs, no LDS, low VGPR).
// Block handles 4 output cols/layer; wave jl owns j = bid*4+jl; lane = 2 K-slices x 32 rows.
struct MlpParams {
    const float* in0;
    float* bufA; float* bufB;
    const float* w[7]; const float* b[7];
    float* out;
};

__device__ __forceinline__ float fc_dot64(const float* __restrict__ in, const float* __restrict__ W,
                                          int j, int n, int ks, int K4) {
    const float4* ip = (const float4*)(in + (size_t)n * (K4 * 4));
    const float4* wp = (const float4*)(W  + (size_t)j * (K4 * 4));
    const int half = K4 >> 1;
    const int s = ks * half, e = s + half;
    float acc0 = 0.f, acc1 = 0.f;   // 2 chains for FMA-latency ILP
    for (int i = s; i + 1 < e; i += 2) {
        float4 a = ip[i],   w0 = wp[i];
        float4 c = ip[i+1], w1 = wp[i+1];
        acc0 = fmaf(a.x, w0.x, fmaf(a.y, w0.y, fmaf(a.z, w0.z, fmaf(a.w, w0.w, acc0))));
        acc1 = fmaf(c.x, w1.x, fmaf(c.y, w1.y, fmaf(c.z, w1.z, fmaf(c.w, w1.w, acc1))));
    }
    if (half & 1) { float4 a = ip[e-1], w0 = wp[e-1];
        acc0 = fmaf(a.x, w0.x, fmaf(a.y, w0.y, fmaf(a.z, w0.z, fmaf(a.w, w0.w, acc0)))); }
    float acc = acc0 + acc1;
    acc += __shfl_xor(acc, 32, 64);   // combine the 2 K-slices (same n, lane^32)
    return acc;
}

__global__ __launch_bounds__(256)
void mlp_kernel(MlpParams p)
{
    cg::grid_group grid = cg::this_grid();
    const int t = threadIdx.x;
    const int jl = t >> 6, lane = t & 63;
    const int ks = lane >> 5, n = lane & 31;
    const int j = blockIdx.x * 4 + jl;     // 0..999

    const float* src = p.in0;
    #pragma unroll
    for (int l = 0; l < 6; ++l) {
        float* dst = (l & 1) ? p.bufB : p.bufA;
        const int K4 = (l == 0) ? 282 : 250;   // K=1128 / 1000
        float acc = fc_dot64(src, p.w[l], j, n, ks, K4);
        if (ks == 0) {
            float r = acc + p.b[l][j];
            dst[(size_t)n * 1000 + j] = fmaxf(r, 0.f);
        }
        grid.sync();
        src = dst;
    }
    if (blockIdx.x == 0 && jl == 0) {      // final layer: J=1
        float acc = fc_dot64(src, p.w[6], 0, n, ks, 250);
        if (ks == 0) p.out[n] = acc + p.b[6][0];
    }
}

// ---------- FC fallback (verified round-12 path) ----------
template<int RELU>
__global__ __launch_bounds__(512)
void fc_kernel(const float* __restrict__ in, const float* __restrict__ W,
               const float* __restrict__ bias, float* __restrict__ out,
               int K, int J)
{
    const int j  = blockIdx.x;
    const int ks = threadIdx.x & 15;
    const int n  = threadIdx.x >> 4;    // 0..31
    const int K4 = K >> 2;
    const float4* ip = (const float4*)(in + (size_t)n * K);
    const float4* wp = (const float4*)(W  + (size_t)j * K);
    float acc = 0.f;
    #pragma unroll 4
    for (int i = ks; i < K4; i += 16) {
        float4 a = ip[i], b = wp[i];
        acc = fmaf(a.x, b.x, fmaf(a.y, b.y, fmaf(a.z, b.z, fmaf(a.w, b.w, acc))));
    }
    #pragma unroll
    for (int off = 1; off < 16; off <<= 1) acc += __shfl_xor(acc, off, 64);
    if (ks == 0) {
        float r = acc + bias[j];
        if (RELU) r = fmaxf(r, 0.f);
        out[(size_t)n * J + j] = r;
    }
}

extern "C" void kernel_launch(void* const* d_in, const int* in_sizes, int n_in,
                              void* d_out, int out_size, void* d_ws, size_t ws_size,
                              hipStream_t stream)
{
    const float* X1     = (const float*)d_in[0];
    const float* X2     = (const float*)d_in[1];
    const float* M1     = (const float*)d_in[2];
    const float* M2     = (const float*)d_in[3];
    const float* attn_w = (const float*)d_in[4];
    const float* g2d    = (const float*)d_in[5];
    const float* b2d    = (const float*)d_in[6];
    const float* g1     = (const float*)d_in[7];
    const float* b1     = (const float*)d_in[8];
    const float* fcw[7] = {(const float*)d_in[9],  (const float*)d_in[11], (const float*)d_in[13],
                           (const float*)d_in[15], (const float*)d_in[17], (const float*)d_in[19],
                           (const float*)d_in[21]};
    const float* fcb[7] = {(const float*)d_in[10], (const float*)d_in[12], (const float*)d_in[14],
                           (const float*)d_in[16], (const float*)d_in[18], (const float*)d_in[20],
                           (const float*)d_in[22]};

    // ws layout (floats)
    float*  xout    = (float*)d_ws;                        // 36096
    float*  feats   = xout + 36096;                        // 36096
    float*  partialf= feats + 36096;                       // 36096
    float4* partial = (float4*)partialf;                   // 1128*8 float4
    float4* coefs   = (float4*)(partialf + 36096);         // 4512 floats
    float*  uA      = partialf + 36096 + 4512;             // 128 (u 13, sA 1, Btri 91)
    float*  hA      = uA + 128;                            // 32000
    float*  hB      = hA + 32000;                          // 32000

    stats_kernel<<<dim3(A_GROUPS * D_CH), dim3(256), 0, stream>>>(X1, X2, partial);
    coef_kernel<<<dim3(5), dim3(256), 0, stream>>>(partial, attn_w, g2d, b2d, coefs, uA);
    attend_kernel<<<dim3(18048), dim3(128), 0, stream>>>(X1, X2, M1, M2, coefs, uA, feats);
    bn1_kernel<<<dim3(141), dim3(256), 0, stream>>>(feats, g1, b1, xout);

    MlpParams mp;
    mp.in0 = xout; mp.bufA = hA; mp.bufB = hB; mp.out = (float*)d_out;
    for (int l = 0; l < 7; ++l) { mp.w[l] = fcw[l]; mp.b[l] = fcb[l]; }
    void* kp[] = { &mp };
    hipError_t ce = hipLaunchCooperativeKernel(reinterpret_cast<const void*>(&mlp_kernel),
                                               dim3(250), dim3(256), kp, 0, stream);
    if (ce != hipSuccess) {
        // fallback: verified 8-launch chain (deterministic per environment)
        fc_kernel<1><<<dim3(1000), dim3(512), 0, stream>>>(xout, fcw[0], fcb[0], hA, 1128, 1000);
        const float* cur = hA; float* nxt = hB;
        for (int l = 1; l < 6; ++l) {
            fc_kernel<1><<<dim3(1000), dim3(512), 0, stream>>>(cur, fcw[l], fcb[l], nxt, 1000, 1000);
            const float* tmp = cur; cur = nxt; nxt = (float*)tmp;
        }
        fc_kernel<0><<<dim3(1), dim3(512), 0, stream>>>(cur, fcw[6], fcb[6], (float*)d_out, 1000, 1);
    }
}

// Round 15
// 278.349 us; speedup vs baseline: 2.0763x; 2.0763x over previous
//
#include <hip/hip_runtime.h>
#include <math.h>

#define N_SPK 32
#define D_CH 1128
#define V_FR 100
#define NFEAT 13
#define CHUNK (V_FR * NFEAT)   // 1300 floats per (b,d) slab
#define CHUNK4 (CHUNK / 4)     // 325 float4s
#define BN_EPS 1e-5f
#define A_GROUPS 8             // stats kernel: 8 groups of 4 speakers
#define A_SPK 4
// uA layout: [0..12] u, [13] sA, [14..104] Btri (upper-tri of A+A^T, diag=A_ii)
#define UOFF_SA 13
#define UOFF_B  14
#define TRI(i, j) ((i) * NFEAT - (i) * ((i) - 1) / 2 + ((j) - (i)))   // j >= i

struct F4 { float a, b, c, d; };   // natural align 4 -> legal 16B load at 4B alignment

__device__ __forceinline__ float wave_sum(float v) {
    #pragma unroll
    for (int off = 1; off < 64; off <<= 1) v += __shfl_xor(v, off, 64);
    return v;
}
__device__ __forceinline__ float tanh_fast(float x) {
    // 1 - 2/(e^{2x}+1); v_exp + v_rcp. Saturates to +/-1 correctly.
    float e = __expf(2.f * x);
    return fmaf(-2.f, __builtin_amdgcn_rcpf(e + 1.f), 1.f);
}

// ---------- A: bn2d partial stats. grid = A_GROUPS x D, block 256 ----------
// At the HBM roofline: 750MB in ~110us (~6.8 TB/s read).
__global__ __launch_bounds__(256)
void stats_kernel(const float* __restrict__ X1, const float* __restrict__ X2,
                  float4* __restrict__ partial)   // [D][A_GROUPS] = {s1,q1,s2,q2}
{
    const int tid  = threadIdx.x;
    const int wave = tid >> 6, lane = tid & 63;
    const int d  = blockIdx.x % D_CH;
    const int g  = blockIdx.x / D_CH;    // 0..7
    const int b0 = g * A_SPK;
    __shared__ float red[4][4];

    float s1 = 0.f, q1 = 0.f, s2 = 0.f, q2 = 0.f;
    #pragma unroll
    for (int c = 0; c < A_SPK; ++c) {
        const float4* p1 = (const float4*)(X1 + ((size_t)(b0 + c) * D_CH + d) * CHUNK);
        const float4* p2 = (const float4*)(X2 + ((size_t)(b0 + c) * D_CH + d) * CHUNK);
        for (int pos = tid; pos < CHUNK4; pos += 256) {
            float4 v = p1[pos];
            s1 += v.x + v.y + v.z + v.w;
            q1 += fmaf(v.x, v.x, fmaf(v.y, v.y, fmaf(v.z, v.z, v.w * v.w)));
            float4 w = p2[pos];
            s2 += w.x + w.y + w.z + w.w;
            q2 += fmaf(w.x, w.x, fmaf(w.y, w.y, fmaf(w.z, w.z, w.w * w.w)));
        }
    }
    s1 = wave_sum(s1); q1 = wave_sum(q1); s2 = wave_sum(s2); q2 = wave_sum(q2);
    if (lane == 0) { red[wave][0] = s1; red[wave][1] = q1; red[wave][2] = s2; red[wave][3] = q2; }
    __syncthreads();
    if (tid == 0) {
        float S1 = 0.f, Q1 = 0.f, S2 = 0.f, Q2 = 0.f;
        for (int w = 0; w < 4; ++w) { S1 += red[w][0]; Q1 += red[w][1]; S2 += red[w][2]; Q2 += red[w][3]; }
        partial[d * A_GROUPS + g] = make_float4(S1, Q1, S2, Q2);
    }
}

// ---------- B: finalize coefs per d; block 0 also precomputes u, sA, Btri ----------
__global__ __launch_bounds__(256)
void coef_kernel(const float4* __restrict__ partial, const float* __restrict__ attn_w,
                 const float* __restrict__ g2d, const float* __restrict__ b2d,
                 float4* __restrict__ coefs, float* __restrict__ uA)
{
    const int d = blockIdx.x * 256 + threadIdx.x;
    if (blockIdx.x == 0 && threadIdx.x < NFEAT) {
        int i = threadIdx.x;
        float s = 0.f;
        for (int j = 0; j < NFEAT; ++j) s += attn_w[i * NFEAT + j] + attn_w[j * NFEAT + i];
        uA[i] = s;                       // u = A*1 + A^T*1 (same for A=W^T as for W)
    }
    if (blockIdx.x == 0 && threadIdx.x == NFEAT) {
        float s = 0.f;
        for (int k = 0; k < NFEAT * NFEAT; ++k) s += attn_w[k];
        uA[UOFF_SA] = s;                 // sA = 1^T A 1
    }
    if (blockIdx.x == 0 && threadIdx.x < NFEAT * NFEAT) {
        int i = threadIdx.x / NFEAT, j = threadIdx.x % NFEAT;
        if (j >= i) {
            float v = (j == i) ? attn_w[i * NFEAT + i]
                               : attn_w[i * NFEAT + j] + attn_w[j * NFEAT + i];
            uA[UOFF_B + TRI(i, j)] = v;  // x^T A x = sum_i x_i * (sum_{j>=i} B_ij x_j)
        }
    }
    if (d >= D_CH) return;
    float S1 = 0.f, Q1 = 0.f, S2 = 0.f, Q2 = 0.f;
    for (int g = 0; g < A_GROUPS; ++g) {
        float4 p = partial[d * A_GROUPS + g];
        S1 += p.x; Q1 += p.y; S2 += p.z; Q2 += p.w;
    }
    const float inv = 1.0f / (float)(N_SPK * V_FR * NFEAT);
    float m1 = S1 * inv, v1 = Q1 * inv - m1 * m1;
    float m2 = S2 * inv, v2 = Q2 * inv - m2 * m2;
    float gd = g2d[d], bd = b2d[d];
    float a1 = gd * rsqrtf(v1 + BN_EPS);
    float a2 = gd * rsqrtf(v2 + BN_EPS);
    coefs[d] = make_float4(a1, bd - m1 * a1, a2, bd - m2 * a2);
}

// per-tensor attention pass. Triangular quadform: 104 fma/frame vs 182.
// Softmax without max-subtraction (logits tanh-bounded); mask folded in as
// a multiplier: e = m * exp(tanh(S)) (masked exp underflowed to 0 anyway).
__device__ __forceinline__ void unit_pass(const float* __restrict__ xg,
                                          const float* __restrict__ mg,
                                          const float* __restrict__ uA,
                                          float aa, float cc, float sA,
                                          int lane, bool has1,
                                          float part[NFEAT], float& den, float& m0out)
{
    // mask loads issued early (long-latency, needed late)
    float m0  = mg[(size_t)lane * NFEAT];
    float m1v = has1 ? mg[(size_t)(lane + 64) * NFEAT] : 0.f;

    float x0[NFEAT], x1[NFEAT];
    {
        const float* p = xg + lane * NFEAT;
        F4 A = *(const F4*)(p); F4 B = *(const F4*)(p + 4); F4 C = *(const F4*)(p + 8);
        x0[0]=A.a; x0[1]=A.b; x0[2]=A.c; x0[3]=A.d;
        x0[4]=B.a; x0[5]=B.b; x0[6]=B.c; x0[7]=B.d;
        x0[8]=C.a; x0[9]=C.b; x0[10]=C.c; x0[11]=C.d;
        x0[12] = p[12];
    }
    if (has1) {
        const float* p = xg + (lane + 64) * NFEAT;
        F4 A = *(const F4*)(p); F4 B = *(const F4*)(p + 4); F4 C = *(const F4*)(p + 8);
        x1[0]=A.a; x1[1]=A.b; x1[2]=A.c; x1[3]=A.d;
        x1[4]=B.a; x1[5]=B.b; x1[6]=B.c; x1[7]=B.d;
        x1[8]=C.a; x1[9]=C.b; x1[10]=C.c; x1[11]=C.d;
        x1[12] = p[12];
    } else {
        #pragma unroll
        for (int i = 0; i < NFEAT; ++i) x1[i] = 0.f;
    }

    // q = x^T A x via upper-triangular B; r = u . x
    float q0 = 0.f, r0 = 0.f, q1f = 0.f, r1f = 0.f;
    #pragma unroll
    for (int i = 0; i < NFEAT; ++i) {
        float bii = uA[UOFF_B + TRI(i, i)];      // uniform -> s_load (scalar pipe)
        float y0 = bii * x0[i];
        float y1 = bii * x1[i];
        #pragma unroll
        for (int j = i + 1; j < NFEAT; ++j) {
            float bij = uA[UOFF_B + TRI(i, j)];  // uniform -> s_load
            y0 = fmaf(bij, x0[j], y0);
            y1 = fmaf(bij, x1[j], y1);
        }
        float ui = uA[i];                        // uniform -> s_load
        q0  = fmaf(x0[i], y0, q0);
        q1f = fmaf(x1[i], y1, q1f);
        r0  = fmaf(ui, x0[i], r0);
        r1f = fmaf(ui, x1[i], r1f);
    }

    float S0 = fmaf(aa * aa, q0,  fmaf(aa * cc, r0,  cc * cc * sA));
    float S1 = fmaf(aa * aa, q1f, fmaf(aa * cc, r1f, cc * cc * sA));

    float e0 = m0 * __expf(tanh_fast(S0));
    float e1 = has1 ? m1v * __expf(tanh_fast(S1)) : 0.f;
    den = e0 + e1;
    #pragma unroll
    for (int i = 0; i < NFEAT; ++i) part[i] = fmaf(e0, x0[i], e1 * x1[i]);
    m0out = m0;
}

// ---------- C: attention, barrier-free, LDS-free. One wave = one (b,d) PAIR ----------
// Best-measured variant (R8: 126us). Five structural alternatives (LDS-staged
// coalesced, 2-pair ILP, higher/lower occupancy) all landed 126-134us with no
// counter saturated -> access-pattern-limited memory-system bound.
__global__ __launch_bounds__(256)
void attend_kernel(const float* __restrict__ X1, const float* __restrict__ X2,
                   const float* __restrict__ M1, const float* __restrict__ M2,
                   const float4* __restrict__ coefs, const float* __restrict__ uA,
                   float* __restrict__ feats)
{
    const int tid  = threadIdx.x;
    const int wave = tid >> 6, lane = tid & 63;

    const int u = blockIdx.x * 4 + wave;      // 0..36095
    const int d = u % D_CH;
    const int b = N_SPK - 1 - (u / D_CH);     // reversed for L3 reuse after stats

    const float4 cf = coefs[d];
    const float a1 = cf.x, c1 = cf.y, a2 = cf.z, c2 = cf.w;
    const float sA = uA[UOFF_SA];

    const size_t base = ((size_t)b * D_CH + d) * CHUNK;
    const bool  has1 = lane < (V_FR - 64);

    float part1[NFEAT], part2[NFEAT], den1, den2, m01, m02;
    unit_pass(X1 + base, M1 + base, uA, a1, c1, sA, lane, has1, part1, den1, m01);
    unit_pass(X2 + base, M2 + base, uA, a2, c2, sA, lane, has1, part2, den2, m02);

    den1 = wave_sum(den1);
    den2 = wave_sum(den2);
    const float w1 = a1 / den1;
    const float w2 = a2 / den2;

    // pair-combined per-lane value; one butterfly reduces a1*t1 - a2*t2
    float q[NFEAT];
    #pragma unroll
    for (int i = 0; i < NFEAT; ++i) q[i] = fmaf(w1, part1[i], -w2 * part2[i]);
    #pragma unroll
    for (int off = 1; off < 64; off <<= 1) {
        #pragma unroll
        for (int i = 0; i < NFEAT; ++i) q[i] += __shfl_xor(q[i], off, 64);
    }

    if (lane == 0) {   // lane 0's m0s are M[b,d,0,0]
        const float dc = c1 - c2;
        float ss = 0.f;
        #pragma unroll
        for (int i = 0; i < NFEAT; ++i) {
            float diff = q[i] + dc;
            ss = fmaf(diff, diff, ss);
        }
        float f  = logf(ss + 1e-5f);
        float pm = (m01 + m02 == 2.0f) ? 1.0f : 0.0f;
        feats[(size_t)b * D_CH + d] = (f + 1.0f) * pm - 1.0f;
    }
}

// ---------- D: BatchNorm1d over speakers. grid = 141, block 256 (8 d's) ----------
__global__ __launch_bounds__(256)
void bn1_kernel(const float* __restrict__ feats, const float* __restrict__ g1,
                const float* __restrict__ b1, float* __restrict__ xout)
{
    const int tid = threadIdx.x;
    const int n = tid & 31, dl = tid >> 5;
    const int d = blockIdx.x * 8 + dl;
    float f = feats[(size_t)n * D_CH + d];
    float s = f, sq = f * f;
    #pragma unroll
    for (int off = 1; off < 32; off <<= 1) { s += __shfl_xor(s, off, 64); sq += __shfl_xor(sq, off, 64); }
    float mean = s * (1.0f / 32.0f);
    float var  = sq * (1.0f / 32.0f) - mean * mean;
    xout[(size_t)n * D_CH + d] = (f - mean) * rsqrtf(var + BN_EPS) * g1[d] + b1[d];
}

// ---------- FC: block 512 = 32 rows x 16 K-slices, shuffle reduce. grid = J ----------
// Cooperative single-kernel alternative measured 8x worse (R14: 310us at 1 block/CU).
template<int RELU>
__global__ __launch_bounds__(512)
void fc_kernel(const float* __restrict__ in, const float* __restrict__ W,
               const float* __restrict__ bias, float* __restrict__ out,
               int K, int J)
{
    const int j  = blockIdx.x;
    const int ks = threadIdx.x & 15;
    const int n  = threadIdx.x >> 4;    // 0..31
    const int K4 = K >> 2;
    const float4* ip = (const float4*)(in + (size_t)n * K);
    const float4* wp = (const float4*)(W  + (size_t)j * K);
    float acc = 0.f;
    #pragma unroll 4
    for (int i = ks; i < K4; i += 16) {
        float4 a = ip[i], b = wp[i];
        acc = fmaf(a.x, b.x, fmaf(a.y, b.y, fmaf(a.z, b.z, fmaf(a.w, b.w, acc))));
    }
    #pragma unroll
    for (int off = 1; off < 16; off <<= 1) acc += __shfl_xor(acc, off, 64);
    if (ks == 0) {
        float r = acc + bias[j];
        if (RELU) r = fmaxf(r, 0.f);
        out[(size_t)n * J + j] = r;
    }
}

extern "C" void kernel_launch(void* const* d_in, const int* in_sizes, int n_in,
                              void* d_out, int out_size, void* d_ws, size_t ws_size,
                              hipStream_t stream)
{
    const float* X1     = (const float*)d_in[0];
    const float* X2     = (const float*)d_in[1];
    const float* M1     = (const float*)d_in[2];
    const float* M2     = (const float*)d_in[3];
    const float* attn_w = (const float*)d_in[4];
    const float* g2d    = (const float*)d_in[5];
    const float* b2d    = (const float*)d_in[6];
    const float* g1     = (const float*)d_in[7];
    const float* b1     = (const float*)d_in[8];
    const float* fcw[7] = {(const float*)d_in[9],  (const float*)d_in[11], (const float*)d_in[13],
                           (const float*)d_in[15], (const float*)d_in[17], (const float*)d_in[19],
                           (const float*)d_in[21]};
    const float* fcb[7] = {(const float*)d_in[10], (const float*)d_in[12], (const float*)d_in[14],
                           (const float*)d_in[16], (const float*)d_in[18], (const float*)d_in[20],
                           (const float*)d_in[22]};

    // ws layout (floats)
    float*  xout    = (float*)d_ws;                        // 36096
    float*  feats   = xout + 36096;                        // 36096
    float*  partialf= feats + 36096;                       // 36096
    float4* partial = (float4*)partialf;                   // 1128*8 float4
    float4* coefs   = (float4*)(partialf + 36096);         // 4512 floats
    float*  uA      = partialf + 36096 + 4512;             // 128 (u 13, sA 1, Btri 91)
    float*  hA      = uA + 128;                            // 32000
    float*  hB      = hA + 32000;                          // 32000

    stats_kernel<<<dim3(A_GROUPS * D_CH), dim3(256), 0, stream>>>(X1, X2, partial);
    coef_kernel<<<dim3(5), dim3(256), 0, stream>>>(partial, attn_w, g2d, b2d, coefs, uA);
    attend_kernel<<<dim3(9024), dim3(256), 0, stream>>>(X1, X2, M1, M2, coefs, uA, feats);
    bn1_kernel<<<dim3(141), dim3(256), 0, stream>>>(feats, g1, b1, xout);

    fc_kernel<1><<<dim3(1000), dim3(512), 0, stream>>>(xout, fcw[0], fcb[0], hA, 1128, 1000);
    const float* cur = hA; float* nxt = hB;
    for (int l = 1; l < 6; ++l) {
        fc_kernel<1><<<dim3(1000), dim3(512), 0, stream>>>(cur, fcw[l], fcb[l], nxt, 1000, 1000);
        const float* tmp = cur; cur = nxt; nxt = (float*)tmp;
    }
    fc_kernel<0><<<dim3(1), dim3(512), 0, stream>>>(cur, fcw[6], fcb[6], (float*)d_out, 1000, 1);
}